// Round 1
// baseline (412.531 us; speedup 1.0000x reference)
//
#include <hip/hip_runtime.h>

#define FEAT1 64
#define FEAT2 16

__global__ void zero_kernel(float4* p, int n4) {
    int i = blockIdx.x * blockDim.x + threadIdx.x;
    if (i < n4) p[i] = make_float4(0.f, 0.f, 0.f, 0.f);
}

__global__ void deg_kernel(const int* __restrict__ src, const int* __restrict__ dst,
                           float* deg_src, float* deg_dst, int E) {
    int e = blockIdx.x * blockDim.x + threadIdx.x;
    if (e < E) {
        atomicAdd(&deg_src[src[e]], 1.0f);
        atomicAdd(&deg_dst[dst[e]], 1.0f);
    }
}

__global__ void norm_kernel(float* deg, int n) {
    int i = blockIdx.x * blockDim.x + threadIdx.x;
    if (i < n) deg[i] = rsqrtf(fmaxf(deg[i], 1.0f));
}

// h1[row][c] = (sum_k X[row][k] * W1[k][c]) * norm_src[row]
// block = 256 threads = 4 rows x 64 cols
__global__ __launch_bounds__(256) void gemm1_kernel(const float* __restrict__ X,
                                                    const float* __restrict__ W1,
                                                    const float* __restrict__ norm_src,
                                                    float* __restrict__ h1, int N) {
    __shared__ float sW[64 * 64];
    __shared__ float sX[4][64];
    int tid = threadIdx.x;
    for (int i = tid; i < 64 * 64; i += 256) sW[i] = W1[i];
    int r = tid >> 6, c = tid & 63;
    int row = blockIdx.x * 4 + r;
    if (row < N) sX[r][c] = X[row * 64 + c];
    __syncthreads();
    if (row < N) {
        float acc = 0.f;
#pragma unroll
        for (int k = 0; k < 64; k++) acc += sX[r][k] * sW[k * 64 + c];
        h1[row * 64 + c] = acc * norm_src[row];
    }
}

// scatter-add h1[src] rows into agg1[dst]; one lane per (edge, feature)
__global__ void scatter64_kernel(const int* __restrict__ src, const int* __restrict__ dst,
                                 const float* __restrict__ h1, float* agg1, int E) {
    int t = blockIdx.x * blockDim.x + threadIdx.x;
    int e = t >> 6;
    int f = t & 63;
    if (e < E) {
        int s = src[e], d = dst[e];
        atomicAdd(&agg1[d * 64 + f], h1[s * 64 + f]);
    }
}

// t[k] = relu(agg1[row][k]*norm_dst[row] + b1[k]);  h2[row][c] = (sum_k t[k]*W2[k][c]) * norm_src[row]
// block = 256 threads = 16 rows x 16 cols
__global__ __launch_bounds__(256) void gemm2_kernel(const float* __restrict__ agg1,
                                                    const float* __restrict__ norm_dst,
                                                    const float* __restrict__ b1,
                                                    const float* __restrict__ W2,
                                                    const float* __restrict__ norm_src,
                                                    float* __restrict__ h2, int N) {
    __shared__ float sW[64 * 16];
    __shared__ float sT[16][65];  // +1 pad: avoid 4-way bank conflict on sT[r][k]
    int tid = threadIdx.x;
    int row0 = blockIdx.x * 16;
    for (int i = tid; i < 64 * 16; i += 256) sW[i] = W2[i];
    for (int l = tid; l < 16 * 64; l += 256) {
        int rr = l >> 6, k = l & 63;
        int row = row0 + rr;
        float v = 0.f;
        if (row < N) v = fmaxf(agg1[row * 64 + k] * norm_dst[row] + b1[k], 0.f);
        sT[rr][k] = v;
    }
    __syncthreads();
    int r = tid >> 4, c = tid & 15;
    int row = row0 + r;
    if (row < N) {
        float acc = 0.f;
#pragma unroll
        for (int k = 0; k < 64; k++) acc += sT[r][k] * sW[k * 16 + c];
        h2[row * 16 + c] = acc * norm_src[row];
    }
}

// scatter-add h2[src] rows into agg2[dst]; 16 lanes per edge
__global__ void scatter16_kernel(const int* __restrict__ src, const int* __restrict__ dst,
                                 const float* __restrict__ h2, float* agg2, int E) {
    int t = blockIdx.x * blockDim.x + threadIdx.x;
    int e = t >> 4;
    int f = t & 15;
    if (e < E) {
        int s = src[e], d = dst[e];
        atomicAdd(&agg2[d * 16 + f], h2[s * 16 + f]);
    }
}

__global__ void final_kernel(const float* __restrict__ agg2, const float* __restrict__ norm_dst,
                             const float* __restrict__ b2, float* __restrict__ out, int total) {
    int i = blockIdx.x * blockDim.x + threadIdx.x;
    if (i < total) {
        int row = i >> 4, c = i & 15;
        out[i] = agg2[i] * norm_dst[row] + b2[c];
    }
}

extern "C" void kernel_launch(void* const* d_in, const int* in_sizes, int n_in,
                              void* d_out, int out_size, void* d_ws, size_t ws_size,
                              hipStream_t stream) {
    const float* X  = (const float*)d_in[0];
    const int* src  = (const int*)d_in[1];
    const int* dst  = (const int*)d_in[2];
    const float* W1 = (const float*)d_in[3];
    const float* b1 = (const float*)d_in[4];
    const float* W2 = (const float*)d_in[5];
    const float* b2 = (const float*)d_in[6];
    float* out = (float*)d_out;

    const int N = in_sizes[0] / FEAT1;  // 50000
    const int E = in_sizes[1];          // 800000

    // workspace layout (floats). Zeroed region first, contiguous:
    //   deg_src/norm_src [N], deg_dst/norm_dst [N], agg1 [N*64], agg2 [N*16]
    // then non-zeroed: h1 [N*64], h2 [N*16]
    float* ws = (float*)d_ws;
    float* norm_src = ws;                 // N
    float* norm_dst = norm_src + N;       // N
    float* agg1     = norm_dst + N;       // N*64
    float* agg2     = agg1 + N * 64;      // N*16
    float* h1       = agg2 + N * 16;      // N*64
    float* h2       = h1 + N * 64;        // N*16

    const int zero_floats = 2 * N + N * 64 + N * 16;  // 4,100,000
    const int zero4 = zero_floats / 4;                // divisible by 4 (N mult of 4)

    zero_kernel<<<(zero4 + 255) / 256, 256, 0, stream>>>((float4*)ws, zero4);
    deg_kernel<<<(E + 255) / 256, 256, 0, stream>>>(src, dst, norm_src, norm_dst, E);
    norm_kernel<<<(2 * N + 255) / 256, 256, 0, stream>>>(norm_src, 2 * N);
    gemm1_kernel<<<(N + 3) / 4, 256, 0, stream>>>(X, W1, norm_src, h1, N);
    scatter64_kernel<<<(E * 64 + 255) / 256, 256, 0, stream>>>(src, dst, h1, agg1, E);
    gemm2_kernel<<<(N + 15) / 16, 256, 0, stream>>>(agg1, norm_dst, b1, W2, norm_src, h2, N);
    scatter16_kernel<<<(E * 16 + 255) / 256, 256, 0, stream>>>(src, dst, h2, agg2, E);
    final_kernel<<<(N * 16 + 255) / 256, 256, 0, stream>>>(agg2, norm_dst, b2, out, N * 16);
}

// Round 2
// 337.688 us; speedup vs baseline: 1.2216x; 1.2216x over previous
//
#include <hip/hip_runtime.h>

#define FEAT1 64
#define FEAT2 16

__global__ void zero_int_kernel(int* p, int n) {
    int i = blockIdx.x * blockDim.x + threadIdx.x;
    if (i < n) p[i] = 0;
}

// histograms of src and dst == degrees
__global__ void hist_kernel(const int* __restrict__ src, const int* __restrict__ dst,
                            int* hist_src, int* hist_dst, int E) {
    int e = blockIdx.x * blockDim.x + threadIdx.x;
    if (e < E) {
        atomicAdd(&hist_src[src[e]], 1);
        atomicAdd(&hist_dst[dst[e]], 1);
    }
}

__global__ void norm_kernel(const int* __restrict__ hist_src, const int* __restrict__ hist_dst,
                            float* norm_src, float* norm_dst, int n) {
    int i = blockIdx.x * blockDim.x + threadIdx.x;
    if (i < n) {
        norm_src[i] = rsqrtf(fmaxf((float)hist_src[i], 1.0f));
        norm_dst[i] = rsqrtf(fmaxf((float)hist_dst[i], 1.0f));
    }
}

// --- 3-kernel exclusive scan of hist_dst -> offs (N <= 256*256) ---
__global__ __launch_bounds__(256) void scan1_kernel(const int* __restrict__ hist, int* offs,
                                                    int* partials, int N) {
    __shared__ int s[256];
    int tid = threadIdx.x;
    int i = blockIdx.x * 256 + tid;
    int v = (i < N) ? hist[i] : 0;
    s[tid] = v;
    __syncthreads();
    for (int off = 1; off < 256; off <<= 1) {
        int t = (tid >= off) ? s[tid - off] : 0;
        __syncthreads();
        s[tid] += t;
        __syncthreads();
    }
    if (i < N) offs[i] = s[tid] - v;  // exclusive within block
    if (tid == 255) partials[blockIdx.x] = s[255];
}

__global__ __launch_bounds__(256) void scan2_kernel(int* partials, int nb) {
    __shared__ int s[256];
    int tid = threadIdx.x;
    int v = (tid < nb) ? partials[tid] : 0;
    s[tid] = v;
    __syncthreads();
    for (int off = 1; off < 256; off <<= 1) {
        int t = (tid >= off) ? s[tid - off] : 0;
        __syncthreads();
        s[tid] += t;
        __syncthreads();
    }
    if (tid < nb) partials[tid] = s[tid] - v;  // exclusive
}

__global__ void scan3_kernel(int* offs, int* cursor, const int* __restrict__ partials, int N) {
    int i = blockIdx.x * blockDim.x + threadIdx.x;
    if (i < N) {
        int v = offs[i] + partials[blockIdx.x * blockDim.x / 256 * 0 + (i >> 8)];
        offs[i] = v;
        cursor[i] = v;
    }
}

// bucket edges by dst: sorted_src[pos] = src
__global__ void reorder_kernel(const int* __restrict__ src, const int* __restrict__ dst,
                               int* cursor, int* sorted_src, int E) {
    int e = blockIdx.x * blockDim.x + threadIdx.x;
    if (e < E) {
        int pos = atomicAdd(&cursor[dst[e]], 1);
        sorted_src[pos] = src[e];
    }
}

// h1[row][c] = (sum_k X[row][k] * W1[k][c]) * norm_src[row]
__global__ __launch_bounds__(256) void gemm1_kernel(const float* __restrict__ X,
                                                    const float* __restrict__ W1,
                                                    const float* __restrict__ norm_src,
                                                    float* __restrict__ h1, int N) {
    __shared__ float sW[64 * 64];
    __shared__ float sX[4][64];
    int tid = threadIdx.x;
    for (int i = tid; i < 64 * 64; i += 256) sW[i] = W1[i];
    int r = tid >> 6, c = tid & 63;
    int row = blockIdx.x * 4 + r;
    if (row < N) sX[r][c] = X[row * 64 + c];
    __syncthreads();
    if (row < N) {
        float acc = 0.f;
#pragma unroll
        for (int k = 0; k < 64; k++) acc += sX[r][k] * sW[k * 64 + c];
        h1[row * 64 + c] = acc * norm_src[row];
    }
}

// gather-aggregate into dst rows (no atomics); fuse norm_dst, b1, relu
// one wave per row, lane = feature
__global__ __launch_bounds__(256) void agg1_kernel(const float* __restrict__ h1,
                                                   const int* __restrict__ sorted_src,
                                                   const int* __restrict__ offs,
                                                   const int* __restrict__ cnt,
                                                   const float* __restrict__ norm_dst,
                                                   const float* __restrict__ b1,
                                                   float* __restrict__ t1, int N) {
    int tid = threadIdx.x;
    int row = blockIdx.x * 4 + (tid >> 6);
    int f = tid & 63;
    if (row >= N) return;
    int start = offs[row], c = cnt[row];
    float acc = 0.f;
    for (int j = 0; j < c; j++) {
        int s = sorted_src[start + j];
        acc += h1[s * 64 + f];
    }
    t1[row * 64 + f] = fmaxf(acc * norm_dst[row] + b1[f], 0.f);
}

// h2[row][c] = (sum_k t1[row][k] * W2[k][c]) * norm_src[row]
__global__ __launch_bounds__(256) void gemm2_kernel(const float* __restrict__ t1,
                                                    const float* __restrict__ W2,
                                                    const float* __restrict__ norm_src,
                                                    float* __restrict__ h2, int N) {
    __shared__ float sW[64 * 16];
    __shared__ float sT[16][65];
    int tid = threadIdx.x;
    int row0 = blockIdx.x * 16;
    for (int i = tid; i < 64 * 16; i += 256) sW[i] = W2[i];
    for (int l = tid; l < 16 * 64; l += 256) {
        int rr = l >> 6, k = l & 63;
        int row = row0 + rr;
        sT[rr][k] = (row < N) ? t1[row * 64 + k] : 0.f;
    }
    __syncthreads();
    int r = tid >> 4, c = tid & 15;
    int row = row0 + r;
    if (row < N) {
        float acc = 0.f;
#pragma unroll
        for (int k = 0; k < 64; k++) acc += sT[r][k] * sW[k * 16 + c];
        h2[row * 16 + c] = acc * norm_src[row];
    }
}

// gather-aggregate layer2 + final epilogue: out = agg*norm_dst + b2
// 16 lanes per row, 16 rows per block
__global__ __launch_bounds__(256) void agg2_kernel(const float* __restrict__ h2,
                                                   const int* __restrict__ sorted_src,
                                                   const int* __restrict__ offs,
                                                   const int* __restrict__ cnt,
                                                   const float* __restrict__ norm_dst,
                                                   const float* __restrict__ b2,
                                                   float* __restrict__ out, int N) {
    int tid = threadIdx.x;
    int row = blockIdx.x * 16 + (tid >> 4);
    int f = tid & 15;
    if (row >= N) return;
    int start = offs[row], c = cnt[row];
    float acc = 0.f;
    for (int j = 0; j < c; j++) {
        int s = sorted_src[start + j];
        acc += h2[s * 16 + f];
    }
    out[row * 16 + f] = acc * norm_dst[row] + b2[f];
}

extern "C" void kernel_launch(void* const* d_in, const int* in_sizes, int n_in,
                              void* d_out, int out_size, void* d_ws, size_t ws_size,
                              hipStream_t stream) {
    const float* X  = (const float*)d_in[0];
    const int* src  = (const int*)d_in[1];
    const int* dst  = (const int*)d_in[2];
    const float* W1 = (const float*)d_in[3];
    const float* b1 = (const float*)d_in[4];
    const float* W2 = (const float*)d_in[5];
    const float* b2 = (const float*)d_in[6];
    float* out = (float*)d_out;

    const int N = in_sizes[0] / FEAT1;  // 50000
    const int E = in_sizes[1];          // 800000

    // workspace layout
    char* w = (char*)d_ws;
    int* hist_src  = (int*)w;                 w += N * 4;
    int* hist_dst  = (int*)w;                 w += N * 4;
    int* offs      = (int*)w;                 w += N * 4;
    int* cursor    = (int*)w;                 w += N * 4;
    int* partials  = (int*)w;                 w += 256 * 4;
    int* sorted_src= (int*)w;                 w += E * 4;
    float* norm_src = (float*)w;              w += N * 4;
    float* norm_dst = (float*)w;              w += N * 4;
    float* h1 = (float*)w;                    w += (size_t)N * 64 * 4;
    float* t1 = (float*)w;                    w += (size_t)N * 64 * 4;
    float* h2 = (float*)w;                    w += (size_t)N * 16 * 4;

    const int nb = (N + 255) / 256;  // 196 scan blocks (must be <= 256)

    zero_int_kernel<<<(2 * N + 255) / 256, 256, 0, stream>>>(hist_src, 2 * N);
    hist_kernel<<<(E + 255) / 256, 256, 0, stream>>>(src, dst, hist_src, hist_dst, E);
    norm_kernel<<<(N + 255) / 256, 256, 0, stream>>>(hist_src, hist_dst, norm_src, norm_dst, N);
    scan1_kernel<<<nb, 256, 0, stream>>>(hist_dst, offs, partials, N);
    scan2_kernel<<<1, 256, 0, stream>>>(partials, nb);
    scan3_kernel<<<nb, 256, 0, stream>>>(offs, cursor, partials, N);
    reorder_kernel<<<(E + 255) / 256, 256, 0, stream>>>(src, dst, cursor, sorted_src, E);
    gemm1_kernel<<<(N + 3) / 4, 256, 0, stream>>>(X, W1, norm_src, h1, N);
    agg1_kernel<<<(N + 3) / 4, 256, 0, stream>>>(h1, sorted_src, offs, hist_dst, norm_dst, b1, t1, N);
    gemm2_kernel<<<(N + 15) / 16, 256, 0, stream>>>(t1, W2, norm_src, h2, N);
    agg2_kernel<<<(N + 15) / 16, 256, 0, stream>>>(h2, sorted_src, offs, hist_dst, norm_dst, b2, out, N);
}

// Round 3
// 284.766 us; speedup vs baseline: 1.4487x; 1.1858x over previous
//
#include <hip/hip_runtime.h>
#include <hip/hip_fp16.h>

#define FEAT1 64
#define FEAT2 16

__global__ void zero_int_kernel(int* p, int n) {
    int i = blockIdx.x * blockDim.x + threadIdx.x;
    if (i < n) p[i] = 0;
}

__global__ void hist_kernel(const int* __restrict__ src, const int* __restrict__ dst,
                            int* hist_src, int* hist_dst, int E) {
    int e = blockIdx.x * blockDim.x + threadIdx.x;
    if (e < E) {
        atomicAdd(&hist_src[src[e]], 1);
        atomicAdd(&hist_dst[dst[e]], 1);
    }
}

// scan1 + fused degree-norm computation
__global__ __launch_bounds__(256) void scan1_kernel(const int* __restrict__ hist_dst,
                                                    const int* __restrict__ hist_src,
                                                    int* offs, int* partials,
                                                    float* norm_src, float* norm_dst, int N) {
    __shared__ int s[256];
    int tid = threadIdx.x;
    int i = blockIdx.x * 256 + tid;
    int v = 0;
    if (i < N) {
        v = hist_dst[i];
        norm_dst[i] = rsqrtf(fmaxf((float)v, 1.0f));
        norm_src[i] = rsqrtf(fmaxf((float)hist_src[i], 1.0f));
    }
    s[tid] = v;
    __syncthreads();
    for (int off = 1; off < 256; off <<= 1) {
        int t = (tid >= off) ? s[tid - off] : 0;
        __syncthreads();
        s[tid] += t;
        __syncthreads();
    }
    if (i < N) offs[i] = s[tid] - v;
    if (tid == 255) partials[blockIdx.x] = s[255];
}

__global__ __launch_bounds__(256) void scan2_kernel(int* partials, int nb) {
    __shared__ int s[256];
    int tid = threadIdx.x;
    int v = (tid < nb) ? partials[tid] : 0;
    s[tid] = v;
    __syncthreads();
    for (int off = 1; off < 256; off <<= 1) {
        int t = (tid >= off) ? s[tid - off] : 0;
        __syncthreads();
        s[tid] += t;
        __syncthreads();
    }
    if (tid < nb) partials[tid] = s[tid] - v;
}

__global__ void scan3_kernel(int* offs, int* cursor, const int* __restrict__ partials, int N) {
    int i = blockIdx.x * blockDim.x + threadIdx.x;
    if (i < N) {
        int v = offs[i] + partials[i >> 8];
        offs[i] = v;
        cursor[i] = v;
    }
}

__global__ void reorder_kernel(const int* __restrict__ src, const int* __restrict__ dst,
                               int* cursor, int* sorted_src, int E) {
    int e = blockIdx.x * blockDim.x + threadIdx.x;
    if (e < E) {
        int pos = atomicAdd(&cursor[dst[e]], 1);
        sorted_src[pos] = src[e];
    }
}

// h1[row][c] = half((sum_k X[row][k]*W1[k][c]) * norm_src[row])
__global__ __launch_bounds__(256) void gemm1_kernel(const float* __restrict__ X,
                                                    const float* __restrict__ W1,
                                                    const float* __restrict__ norm_src,
                                                    __half* __restrict__ h1, int N) {
    __shared__ float sW[64 * 64];
    __shared__ float sX[4][64];
    int tid = threadIdx.x;
    for (int i = tid; i < 64 * 64; i += 256) sW[i] = W1[i];
    int r = tid >> 6, c = tid & 63;
    int row = blockIdx.x * 4 + r;
    if (row < N) sX[r][c] = X[row * 64 + c];
    __syncthreads();
    if (row < N) {
        float acc = 0.f;
#pragma unroll
        for (int k = 0; k < 64; k++) acc += sX[r][k] * sW[k * 64 + c];
        h1[row * 64 + c] = __float2half(acc * norm_src[row]);
    }
}

// gather-aggregate (fp16 rows, 4 edges per wave-iteration), fuse norm_dst+b1+relu
// wave per row: lane = e_off(2b) x fg(4b); feats 4fg..4fg+3 per lane (8B loads)
__global__ __launch_bounds__(256) void agg1_kernel(const __half* __restrict__ h1,
                                                   const int* __restrict__ sorted_src,
                                                   const int* __restrict__ offs,
                                                   const int* __restrict__ cnt,
                                                   const float* __restrict__ norm_dst,
                                                   const float* __restrict__ b1,
                                                   __half* __restrict__ t1, int N) {
    int tid = threadIdx.x;
    int row = blockIdx.x * 4 + (tid >> 6);
    if (row >= N) return;
    int lane = tid & 63;
    int e_off = lane >> 4;   // 0..3
    int fg = lane & 15;      // 0..15, feats 4fg..4fg+3
    int start = offs[row], c = cnt[row];
    float4 acc = make_float4(0.f, 0.f, 0.f, 0.f);
    for (int j = 0; j < c; j += 4) {
        int je = j + e_off;
        if (je < c) {
            int s = sorted_src[start + je];
            uint2 u = ((const uint2*)(h1 + (size_t)s * 64))[fg];
            __half2 p0 = *reinterpret_cast<__half2*>(&u.x);
            __half2 p1 = *reinterpret_cast<__half2*>(&u.y);
            float2 f0 = __half22float2(p0), f1 = __half22float2(p1);
            acc.x += f0.x; acc.y += f0.y; acc.z += f1.x; acc.w += f1.y;
        }
    }
#pragma unroll
    for (int m = 16; m <= 32; m <<= 1) {
        acc.x += __shfl_xor(acc.x, m);
        acc.y += __shfl_xor(acc.y, m);
        acc.z += __shfl_xor(acc.z, m);
        acc.w += __shfl_xor(acc.w, m);
    }
    if (e_off == 0) {
        float nd = norm_dst[row];
        int f0 = fg * 4;
        float r0 = fmaxf(acc.x * nd + b1[f0 + 0], 0.f);
        float r1 = fmaxf(acc.y * nd + b1[f0 + 1], 0.f);
        float r2 = fmaxf(acc.z * nd + b1[f0 + 2], 0.f);
        float r3 = fmaxf(acc.w * nd + b1[f0 + 3], 0.f);
        __half2 o0 = __floats2half2_rn(r0, r1);
        __half2 o1 = __floats2half2_rn(r2, r3);
        uint2 u;
        u.x = *reinterpret_cast<unsigned int*>(&o0);
        u.y = *reinterpret_cast<unsigned int*>(&o1);
        ((uint2*)(t1 + (size_t)row * 64))[fg] = u;
    }
}

// h2[row][c] = half((sum_k t1[row][k]*W2[k][c]) * norm_src[row])
__global__ __launch_bounds__(256) void gemm2_kernel(const __half* __restrict__ t1,
                                                    const float* __restrict__ W2,
                                                    const float* __restrict__ norm_src,
                                                    __half* __restrict__ h2, int N) {
    __shared__ float sW[64 * 16];
    __shared__ float sT[16][65];
    int tid = threadIdx.x;
    int row0 = blockIdx.x * 16;
    for (int i = tid; i < 64 * 16; i += 256) sW[i] = W2[i];
    for (int l = tid; l < 16 * 32; l += 256) {
        int rr = l >> 5, kp = l & 31;
        int row = row0 + rr;
        float2 v = make_float2(0.f, 0.f);
        if (row < N) {
            __half2 h = ((const __half2*)(t1 + (size_t)row * 64))[kp];
            v = __half22float2(h);
        }
        sT[rr][kp * 2] = v.x;
        sT[rr][kp * 2 + 1] = v.y;
    }
    __syncthreads();
    int r = tid >> 4, c = tid & 15;
    int row = row0 + r;
    if (row < N) {
        float acc = 0.f;
#pragma unroll
        for (int k = 0; k < 64; k++) acc += sT[r][k] * sW[k * 16 + c];
        h2[row * 16 + c] = __float2half(acc * norm_src[row]);
    }
}

// gather-aggregate layer2 (fp16 rows of 32B, 8 edges per wave-iteration) + epilogue
// lane = e_off(3b) x fg(3b); feats 2fg,2fg+1 per lane (4B loads)
__global__ __launch_bounds__(256) void agg2_kernel(const __half* __restrict__ h2,
                                                   const int* __restrict__ sorted_src,
                                                   const int* __restrict__ offs,
                                                   const int* __restrict__ cnt,
                                                   const float* __restrict__ norm_dst,
                                                   const float* __restrict__ b2,
                                                   float* __restrict__ out, int N) {
    int tid = threadIdx.x;
    int row = blockIdx.x * 4 + (tid >> 6);
    if (row >= N) return;
    int lane = tid & 63;
    int e_off = lane >> 3;  // 0..7
    int fg = lane & 7;      // feats 2fg, 2fg+1
    int start = offs[row], c = cnt[row];
    float2 acc = make_float2(0.f, 0.f);
    for (int j = 0; j < c; j += 8) {
        int je = j + e_off;
        if (je < c) {
            int s = sorted_src[start + je];
            __half2 h = ((const __half2*)(h2 + (size_t)s * 16))[fg];
            float2 f = __half22float2(h);
            acc.x += f.x; acc.y += f.y;
        }
    }
#pragma unroll
    for (int m = 8; m <= 32; m <<= 1) {
        acc.x += __shfl_xor(acc.x, m);
        acc.y += __shfl_xor(acc.y, m);
    }
    if (e_off == 0) {
        float nd = norm_dst[row];
        float2 o;
        o.x = acc.x * nd + b2[fg * 2];
        o.y = acc.y * nd + b2[fg * 2 + 1];
        ((float2*)(out + (size_t)row * 16))[fg] = o;
    }
}

extern "C" void kernel_launch(void* const* d_in, const int* in_sizes, int n_in,
                              void* d_out, int out_size, void* d_ws, size_t ws_size,
                              hipStream_t stream) {
    const float* X  = (const float*)d_in[0];
    const int* src  = (const int*)d_in[1];
    const int* dst  = (const int*)d_in[2];
    const float* W1 = (const float*)d_in[3];
    const float* b1 = (const float*)d_in[4];
    const float* W2 = (const float*)d_in[5];
    const float* b2 = (const float*)d_in[6];
    float* out = (float*)d_out;

    const int N = in_sizes[0] / FEAT1;  // 50000
    const int E = in_sizes[1];          // 800000

    char* w = (char*)d_ws;
    int* hist_src   = (int*)w;   w += N * 4;
    int* hist_dst   = (int*)w;   w += N * 4;
    int* offs       = (int*)w;   w += N * 4;
    int* cursor     = (int*)w;   w += N * 4;
    int* partials   = (int*)w;   w += 256 * 4;
    int* sorted_src = (int*)w;   w += E * 4;
    float* norm_src = (float*)w; w += N * 4;
    float* norm_dst = (float*)w; w += N * 4;
    __half* h1 = (__half*)w;     w += (size_t)N * 64 * 2;
    __half* t1 = (__half*)w;     w += (size_t)N * 64 * 2;
    __half* h2 = (__half*)w;     w += (size_t)N * 16 * 2;

    const int nb = (N + 255) / 256;  // 196 <= 256

    zero_int_kernel<<<(2 * N + 255) / 256, 256, 0, stream>>>(hist_src, 2 * N);
    hist_kernel<<<(E + 255) / 256, 256, 0, stream>>>(src, dst, hist_src, hist_dst, E);
    scan1_kernel<<<nb, 256, 0, stream>>>(hist_dst, hist_src, offs, partials, norm_src, norm_dst, N);
    scan2_kernel<<<1, 256, 0, stream>>>(partials, nb);
    scan3_kernel<<<nb, 256, 0, stream>>>(offs, cursor, partials, N);
    reorder_kernel<<<(E + 255) / 256, 256, 0, stream>>>(src, dst, cursor, sorted_src, E);
    gemm1_kernel<<<(N + 3) / 4, 256, 0, stream>>>(X, W1, norm_src, h1, N);
    agg1_kernel<<<(N + 3) / 4, 256, 0, stream>>>(h1, sorted_src, offs, hist_dst, norm_dst, b1, t1, N);
    gemm2_kernel<<<(N + 15) / 16, 256, 0, stream>>>(t1, W2, norm_src, h2, N);
    agg2_kernel<<<(N + 3) / 4, 256, 0, stream>>>(h2, sorted_src, offs, hist_dst, norm_dst, b2, out, N);
}